// Round 10
// baseline (7307.507 us; speedup 1.0000x reference)
//
#include <hip/hip_runtime.h>
#include <hip/hip_bf16.h>

#define BB 128
#define SS 16
#define EE 512
#define RR 500
#define G4 2048          // 4*E
#define OUT0 64128       // B*501 : scores chunk first (R0 signature)
#define NSC 501          // R+1
#define NLOSS 2048       // B*16
#define NPAIR 2047       // uniform pair rows m=0..2046 (p==15 junk, never read)

__device__ __forceinline__ float sigm(float x) { return 1.f / (1.f + expf(-x)); }

// ================= device-global pipeline buffers =================
__device__ float g_blstm[G4];
__device__ float g_fcw[EE + 4];          // fc_w, fc_b at [EE]
__device__ float g_qbias[1024];          // fcq_b | fck_b
__device__ float g_Krel[RR * EE];
__device__ float g_cur[BB * SS * EE];    // strided rows m = b*16 + j
__device__ float g_G[BB * SS * G4];
__device__ float g_h1[BB * SS * EE];
__device__ float g_c1[BB * SS * EE];
__device__ float g_h2[BB * SS * EE];     // pair p at row b*16+p
__device__ float g_g2[BB * SS * G4];
__device__ float g_sc[BB * SS];
__device__ float g_hsel[BB * EE];
__device__ float g_qk[BB * 1024];        // q | ksel
__device__ float g_scores[BB * NSC];
__device__ float g_merged[BB * EE];
__device__ float g_ent[BB * SS];
__device__ int   g_sel[BB];

// ================= setup =================
__global__ void k_prep(const float* __restrict__ bih, const float* __restrict__ bhh,
                       const float* __restrict__ fcwv, const float* __restrict__ fcbv,
                       const float* __restrict__ fcqb, const float* __restrict__ fckb) {
    int i = blockIdx.x * blockDim.x + threadIdx.x;   // grid 8*256 = 2048
    if (i < G4) g_blstm[i] = bih[i] + bhh[i];
    if (i < EE) {
        g_fcw[i] = fcwv[i];
        g_qbias[i] = fcqb[i];
        g_qbias[EE + i] = fckb[i];
    }
    if (i == 0) g_fcw[EE] = fcbv[0];
}

__global__ void k_gather(const int* __restrict__ tok, const float* __restrict__ emb) {
    int i = blockIdx.x * blockDim.x + threadIdx.x;
    if (i >= BB * SS * EE) return;
    int e = i & (EE - 1);
    int r = i >> 9;
    int t = tok[r];
    g_cur[i] = emb[(size_t)t * EE + e];
}

// ================= fp32 GEMM tile core =================
// C[m,n] = sum_k A[m,k] * W(n,k) (+bias[n]) (+Dadd[m,n]);  W(n,k) = wtrans ? W[k*ldw+n] : W[n*ldw+k]
#define TM 32
#define TN 64
#define TK 32
__device__ __forceinline__ void gemm_dev(
    const float* __restrict__ A, int lda,
    const float* __restrict__ W, int ldw, int wtrans,
    const float* __restrict__ bias, const float* __restrict__ Dadd, int ldd,
    float* __restrict__ C, int ldc, int M, int N, int K)
{
    __shared__ float As[TM][TK + 1];
    __shared__ float Ws[TN][TK + 1];
    int tid = threadIdx.x;
    int mt = blockIdx.y * TM;
    int nt = blockIdx.x * TN;
    int tr = tid >> 4;
    int tc = tid & 15;
    float acc[2][4] = {{0.f,0.f,0.f,0.f},{0.f,0.f,0.f,0.f}};

    int ea = tid * 4;
    int ra = ea >> 5;            // 0..31
    int ka = ea & 31;
    int gmA = mt + ra;
    bool rokA = gmA < M;
    int ew = tid * 8;
    int rw = ew >> 5;            // 0..63
    int kw = ew & 31;
    int gnW = nt + rw;
    bool rokW = gnW < N;

    for (int kt = 0; kt < K; kt += TK) {
        #pragma unroll
        for (int i = 0; i < 4; i++) {
            int gk = kt + ka + i;
            float v = 0.f;
            if (rokA && gk < K) v = A[(size_t)gmA * lda + gk];
            As[ra][ka + i] = v;
        }
        #pragma unroll
        for (int i = 0; i < 8; i++) {
            int gk = kt + kw + i;
            float v = 0.f;
            if (rokW && gk < K)
                v = wtrans ? W[(size_t)gk * ldw + gnW] : W[(size_t)gnW * ldw + gk];
            Ws[rw][kw + i] = v;
        }
        __syncthreads();
        #pragma unroll
        for (int kk = 0; kk < TK; kk++) {
            float a0 = As[2 * tr][kk];
            float a1 = As[2 * tr + 1][kk];
            float w0 = Ws[4 * tc + 0][kk];
            float w1 = Ws[4 * tc + 1][kk];
            float w2 = Ws[4 * tc + 2][kk];
            float w3 = Ws[4 * tc + 3][kk];
            acc[0][0] += a0 * w0; acc[0][1] += a0 * w1; acc[0][2] += a0 * w2; acc[0][3] += a0 * w3;
            acc[1][0] += a1 * w0; acc[1][1] += a1 * w1; acc[1][2] += a1 * w2; acc[1][3] += a1 * w3;
        }
        __syncthreads();
    }
    #pragma unroll
    for (int i = 0; i < 2; i++) {
        int gm = mt + 2 * tr + i;
        if (gm >= M) continue;
        #pragma unroll
        for (int j = 0; j < 4; j++) {
            int gn = nt + 4 * tc + j;
            if (gn >= N) continue;
            float v = acc[i][j];
            if (bias) v += bias[gn];
            if (Dadd) v += Dadd[(size_t)gm * ldd + gn];
            C[(size_t)gm * ldc + gn] = v;
        }
    }
}

// ---- GEMM wrappers (weights read directly from d_in as fp32) ----
__global__ __launch_bounds__(256) void kg_Krel(const float* __restrict__ emb, const float* __restrict__ fckw) {
    gemm_dev(emb, EE, fckw, EE, 0, g_qbias + EE, nullptr, 0, g_Krel, EE, RR, EE, EE);
}
__global__ __launch_bounds__(256) void kg_G(const float* __restrict__ wih) {
    gemm_dev(g_cur, EE, wih, EE, 0, g_blstm, nullptr, 0, g_G, G4, BB * SS, G4, EE);
}
__global__ __launch_bounds__(256) void kg_g2(const float* __restrict__ whh) {
    gemm_dev(g_h1, EE, whh, EE, 0, nullptr, g_G + G4, G4, g_g2, G4, NPAIR, G4, EE);
}
__global__ __launch_bounds__(256) void kg_q(const float* __restrict__ fcqw) {
    gemm_dev(g_hsel, EE, fcqw, EE, 0, g_qbias, nullptr, 0, g_qk, 1024, BB, EE, EE);
}
__global__ __launch_bounds__(256) void kg_k(const float* __restrict__ fckw) {
    gemm_dev(g_hsel, EE, fckw, EE, 0, g_qbias + EE, nullptr, 0, g_qk + EE, 1024, BB, EE, EE);
}
__global__ __launch_bounds__(256) void kg_scores() {
    gemm_dev(g_qk, 1024, g_Krel, EE, 0, nullptr, nullptr, 0, g_scores, NSC, BB, RR, EE);
}
__global__ __launch_bounds__(256) void kg_merged(const float* __restrict__ emb) {
    gemm_dev(g_scores, NSC, emb, EE, 1, nullptr, nullptr, 0, g_merged, EE, BB, EE, RR);
}

// ================= LSTM elementwise =================
__global__ void k_h1() {
    int idx = blockIdx.x * blockDim.x + threadIdx.x;
    if (idx >= BB * SS * EE) return;
    int m = idx >> 9;
    int e = idx & (EE - 1);
    const float* g = g_G + (size_t)m * G4;
    float c = sigm(g[e]) * tanhf(g[1024 + e]);
    g_c1[idx] = c;
    g_h1[idx] = sigm(g[1536 + e]) * tanhf(c);
}

__global__ __launch_bounds__(256) void k_h2() {
    int m = blockIdx.x;                 // 0..2046
    const float* g = g_g2 + (size_t)m * G4;
    __shared__ float red[256];
    float part = 0.f;
    for (int e = threadIdx.x; e < EE; e += 256) {
        float c = sigm(g[512 + e]) * g_c1[(size_t)m * EE + e] + sigm(g[e]) * tanhf(g[1024 + e]);
        float h = sigm(g[1536 + e]) * tanhf(c);
        g_h2[(size_t)m * EE + e] = h;
        part += h * g_fcw[e];
    }
    red[threadIdx.x] = part;
    __syncthreads();
    for (int s = 128; s > 0; s >>= 1) {
        if (threadIdx.x < s) red[threadIdx.x] += red[threadIdx.x + s];
        __syncthreads();
    }
    if (threadIdx.x == 0) g_sc[m] = sigm(red[0] + g_fcw[EE]);
}

// ================= argmax + h-select =================
__global__ __launch_bounds__(64) void k_sel(int P) {
    int b = blockIdx.x;
    __shared__ int ssel;
    if (threadIdx.x == 0) {
        float best = -1e30f; int bi = 0;
        for (int p = 0; p < P; p++) {
            float v = g_sc[b * SS + p];
            if (v > best) { best = v; bi = p; }
        }
        g_sel[b] = bi; ssel = bi;
    }
    __syncthreads();
    int bi = ssel;
    for (int e = threadIdx.x; e < EE; e += 64)
        g_hsel[b * EE + e] = g_h2[(size_t)(b * SS + bi) * EE + e];
}

// ================= softmax / entropy =================
// finalFlag: writes scaled scores DIRECTLY to out[b*NSC + i] as FLOAT (scores chunk at flat[0:OUT0]).
__global__ __launch_bounds__(256) void k_soft(int col, int finalFlag, float* __restrict__ out) {
    int b = blockIdx.x;
    __shared__ float sh[256];
    __shared__ float srow[NSC];
    float part = 0.f;
    for (int e = threadIdx.x; e < EE; e += 256)
        part += g_qk[(size_t)b * 1024 + e] * g_qk[(size_t)b * 1024 + 512 + e];
    sh[threadIdx.x] = part; __syncthreads();
    for (int s = 128; s > 0; s >>= 1) { if (threadIdx.x < s) sh[threadIdx.x] += sh[threadIdx.x + s]; __syncthreads(); }
    const float isq = 0.044194173824159216f;   // 1/sqrt(512)
    if (threadIdx.x == 0) srow[RR] = sh[0] * isq;
    __syncthreads();
    for (int i = threadIdx.x; i < RR; i += 256) srow[i] = g_scores[(size_t)b * NSC + i] * isq;
    __syncthreads();
    float mx = -1e30f;
    for (int i = threadIdx.x; i < NSC; i += 256) mx = fmaxf(mx, srow[i]);
    sh[threadIdx.x] = mx; __syncthreads();
    for (int s = 128; s > 0; s >>= 1) { if (threadIdx.x < s) sh[threadIdx.x] = fmaxf(sh[threadIdx.x], sh[threadIdx.x + s]); __syncthreads(); }
    mx = sh[0]; __syncthreads();
    float zp = 0.f;
    for (int i = threadIdx.x; i < NSC; i += 256) zp += expf(srow[i] - mx);
    sh[threadIdx.x] = zp; __syncthreads();
    for (int s = 128; s > 0; s >>= 1) { if (threadIdx.x < s) sh[threadIdx.x] += sh[threadIdx.x + s]; __syncthreads(); }
    float lse = mx + logf(sh[0]);
    __syncthreads();
    float ep = 0.f;
    for (int i = threadIdx.x; i < NSC; i += 256) {
        float p = expf(srow[i] - lse);
        ep += p * (lse - srow[i]);
        if (finalFlag) {
            out[(size_t)b * NSC + i] = srow[i];          // final raw scaled scores
        } else {
            g_scores[(size_t)b * NSC + i] = p;           // prob for merged-gemm
        }
    }
    sh[threadIdx.x] = ep; __syncthreads();
    for (int s = 128; s > 0; s >>= 1) { if (threadIdx.x < s) sh[threadIdx.x] += sh[threadIdx.x + s]; __syncthreads(); }
    if (threadIdx.x == 0) g_ent[b * SS + col] = sh[0];
}

// ================= merge + shift =================
__global__ __launch_bounds__(512) void k_upd(int L) {
    int b = blockIdx.x;
    int e = threadIdx.x;
    int s = g_sel[b];
    float p500 = g_scores[(size_t)b * NSC + RR];
    float newv = g_merged[(size_t)b * EE + e] + p500 * g_hsel[(size_t)b * EE + e];
    size_t base = (size_t)b * SS * EE;
    for (int j = s + 1; j <= L - 2; j++)
        g_cur[base + (size_t)j * EE + e] = g_cur[base + (size_t)(j + 1) * EE + e];
    g_cur[base + (size_t)s * EE + e] = newv;
}

// ================= loss-region writer (flat[OUT0 : OUT0+2048], FLOAT) =================
__global__ void k_out(float* __restrict__ out) {
    int j = blockIdx.x * blockDim.x + threadIdx.x;
    if (j >= NLOSS) return;
    out[OUT0 + j] = ((j & 15) == 14) ? 0.f : g_ent[j];
}

// ================= host launch =================
extern "C" void kernel_launch(void* const* d_in, const int* in_sizes, int n_in,
                              void* d_out, int out_size, void* d_ws, size_t ws_size,
                              hipStream_t stream) {
    const int*   tokens = (const int*)d_in[0];
    const float* emb    = (const float*)d_in[1];
    const float* wih    = (const float*)d_in[2];
    const float* whh    = (const float*)d_in[3];
    const float* bih    = (const float*)d_in[4];
    const float* bhh    = (const float*)d_in[5];
    const float* fcwv   = (const float*)d_in[6];
    const float* fcbv   = (const float*)d_in[7];
    const float* fcqw   = (const float*)d_in[8];
    const float* fcqb   = (const float*)d_in[9];
    const float* fckw   = (const float*)d_in[10];
    const float* fckb   = (const float*)d_in[11];
    float* out = (float*)d_out;

    auto grid2 = [](int M, int N) { return dim3((unsigned)((N + TN - 1) / TN), (unsigned)((M + TM - 1) / TM)); };

    k_prep<<<dim3(8), dim3(256), 0, stream>>>(bih, bhh, fcwv, fcbv, fcqb, fckb);
    kg_Krel<<<grid2(RR, EE), dim3(256), 0, stream>>>(emb, fckw);
    k_gather<<<dim3((BB * SS * EE + 255) / 256), dim3(256), 0, stream>>>(tokens, emb);

    auto lstm_all = [&]() {
        kg_G<<<grid2(BB * SS, G4), dim3(256), 0, stream>>>(wih);
        k_h1<<<dim3((BB * SS * EE + 255) / 256), dim3(256), 0, stream>>>();
        kg_g2<<<grid2(NPAIR, G4), dim3(256), 0, stream>>>(whh);
        k_h2<<<dim3(NPAIR), dim3(256), 0, stream>>>();
    };

    for (int L = SS; L >= 3; L--) {
        lstm_all();
        k_sel<<<dim3(BB), dim3(64), 0, stream>>>(L - 1);
        kg_q<<<grid2(BB, EE), dim3(256), 0, stream>>>(fcqw);
        kg_k<<<grid2(BB, EE), dim3(256), 0, stream>>>(fckw);
        kg_scores<<<grid2(BB, RR), dim3(256), 0, stream>>>();
        k_soft<<<dim3(BB), dim3(256), 0, stream>>>(SS - L, 0, out);
        kg_merged<<<grid2(BB, EE), dim3(256), 0, stream>>>(emb);
        k_upd<<<dim3(BB), dim3(512), 0, stream>>>(L);
    }

    // L == 2: pair 0's h2 is the final x; final k_soft writes the scores chunk directly
    lstm_all();
    k_sel<<<dim3(BB), dim3(64), 0, stream>>>(1);
    kg_q<<<grid2(BB, EE), dim3(256), 0, stream>>>(fcqw);
    kg_k<<<grid2(BB, EE), dim3(256), 0, stream>>>(fckw);
    kg_scores<<<grid2(BB, RR), dim3(256), 0, stream>>>();
    k_soft<<<dim3(BB), dim3(256), 0, stream>>>(15, 1, out);

    k_out<<<dim3(8), dim3(256), 0, stream>>>(out);

    (void)in_sizes; (void)n_in; (void)out_size; (void)d_ws; (void)ws_size;
}

// Round 11
// 3351.159 us; speedup vs baseline: 2.1806x; 2.1806x over previous
//
#include <hip/hip_runtime.h>
#include <hip/hip_bf16.h>

#define BB 128
#define SS 16
#define EE 512
#define RR 500
#define G4 2048          // 4*E
#define OUT0 64128       // B*501 : scores chunk first
#define NSC 501          // R+1
#define NLOSS 2048       // B*16
#define NPAIR 2047       // uniform pair rows m=0..2046 (p==15 junk, never read)

__device__ __forceinline__ float sigm(float x) { return 1.f / (1.f + expf(-x)); }

// ================= device-global pipeline buffers =================
__device__ float g_blstm[G4];
__device__ float g_fcw[EE + 4];          // fc_w, fc_b at [EE]
__device__ float g_qbias[1024];          // fcq_b | fck_b
__device__ float g_Krel[RR * EE];
__device__ float g_cur[BB * SS * EE];    // strided rows m = b*16 + j
__device__ float g_G[BB * SS * G4];      // persistent, shifted incrementally
__device__ float g_h1[BB * SS * EE];     // persistent
__device__ float g_c1[BB * SS * EE];     // persistent
__device__ float g_h2[BB * SS * EE];     // persistent; pair p at row b*16+p
__device__ float g_g2[BB * SS * G4];     // scratch (init full pass); first 256 rows reused per-iter
__device__ float g_sc[BB * SS];          // persistent
__device__ float g_hsel[BB * EE];
__device__ float g_qk[BB * 1024];        // q | ksel
__device__ float g_scores[BB * NSC];
__device__ float g_merged[BB * EE];
__device__ float g_ent[BB * SS];
__device__ int   g_sel[BB];

// ================= setup =================
__global__ void k_prep(const float* __restrict__ bih, const float* __restrict__ bhh,
                       const float* __restrict__ fcwv, const float* __restrict__ fcbv,
                       const float* __restrict__ fcqb, const float* __restrict__ fckb) {
    int i = blockIdx.x * blockDim.x + threadIdx.x;   // grid 8*256 = 2048
    if (i < G4) g_blstm[i] = bih[i] + bhh[i];
    if (i < EE) {
        g_fcw[i] = fcwv[i];
        g_qbias[i] = fcqb[i];
        g_qbias[EE + i] = fckb[i];
    }
    if (i == 0) g_fcw[EE] = fcbv[0];
}

__global__ void k_gather(const int* __restrict__ tok, const float* __restrict__ emb) {
    int i = blockIdx.x * blockDim.x + threadIdx.x;
    if (i >= BB * SS * EE) return;
    int e = i & (EE - 1);
    int r = i >> 9;
    int t = tok[r];
    g_cur[i] = emb[(size_t)t * EE + e];
}

// ================= fp32 GEMM tile core =================
// C[m,n] = sum_k A[m,k] * W(n,k) (+bias[n]) (+Dadd[m,n]);  W(n,k) = wtrans ? W[k*ldw+n] : W[n*ldw+k]
#define TM 32
#define TN 64
#define TK 32
__device__ __forceinline__ void gemm_dev(
    const float* __restrict__ A, int lda,
    const float* __restrict__ W, int ldw, int wtrans,
    const float* __restrict__ bias, const float* __restrict__ Dadd, int ldd,
    float* __restrict__ C, int ldc, int M, int N, int K)
{
    __shared__ float As[TM][TK + 1];
    __shared__ float Ws[TN][TK + 1];
    int tid = threadIdx.x;
    int mt = blockIdx.y * TM;
    int nt = blockIdx.x * TN;
    int tr = tid >> 4;
    int tc = tid & 15;
    float acc[2][4] = {{0.f,0.f,0.f,0.f},{0.f,0.f,0.f,0.f}};

    int ea = tid * 4;
    int ra = ea >> 5;
    int ka = ea & 31;
    int gmA = mt + ra;
    bool rokA = gmA < M;
    int ew = tid * 8;
    int rw = ew >> 5;
    int kw = ew & 31;
    int gnW = nt + rw;
    bool rokW = gnW < N;

    for (int kt = 0; kt < K; kt += TK) {
        #pragma unroll
        for (int i = 0; i < 4; i++) {
            int gk = kt + ka + i;
            float v = 0.f;
            if (rokA && gk < K) v = A[(size_t)gmA * lda + gk];
            As[ra][ka + i] = v;
        }
        #pragma unroll
        for (int i = 0; i < 8; i++) {
            int gk = kt + kw + i;
            float v = 0.f;
            if (rokW && gk < K)
                v = wtrans ? W[(size_t)gk * ldw + gnW] : W[(size_t)gnW * ldw + gk];
            Ws[rw][kw + i] = v;
        }
        __syncthreads();
        #pragma unroll
        for (int kk = 0; kk < TK; kk++) {
            float a0 = As[2 * tr][kk];
            float a1 = As[2 * tr + 1][kk];
            float w0 = Ws[4 * tc + 0][kk];
            float w1 = Ws[4 * tc + 1][kk];
            float w2 = Ws[4 * tc + 2][kk];
            float w3 = Ws[4 * tc + 3][kk];
            acc[0][0] += a0 * w0; acc[0][1] += a0 * w1; acc[0][2] += a0 * w2; acc[0][3] += a0 * w3;
            acc[1][0] += a1 * w0; acc[1][1] += a1 * w1; acc[1][2] += a1 * w2; acc[1][3] += a1 * w3;
        }
        __syncthreads();
    }
    #pragma unroll
    for (int i = 0; i < 2; i++) {
        int gm = mt + 2 * tr + i;
        if (gm >= M) continue;
        #pragma unroll
        for (int j = 0; j < 4; j++) {
            int gn = nt + 4 * tc + j;
            if (gn >= N) continue;
            float v = acc[i][j];
            if (bias) v += bias[gn];
            if (Dadd) v += Dadd[(size_t)gm * ldd + gn];
            C[(size_t)gm * ldc + gn] = v;
        }
    }
}

// ---- full GEMM wrappers ----
__global__ __launch_bounds__(256) void kg_Krel(const float* __restrict__ emb, const float* __restrict__ fckw) {
    gemm_dev(emb, EE, fckw, EE, 0, g_qbias + EE, nullptr, 0, g_Krel, EE, RR, EE, EE);
}
__global__ __launch_bounds__(256) void kg_G(const float* __restrict__ wih) {
    gemm_dev(g_cur, EE, wih, EE, 0, g_blstm, nullptr, 0, g_G, G4, BB * SS, G4, EE);
}
__global__ __launch_bounds__(256) void kg_g2(const float* __restrict__ whh) {
    gemm_dev(g_h1, EE, whh, EE, 0, nullptr, g_G + G4, G4, g_g2, G4, NPAIR, G4, EE);
}
__global__ __launch_bounds__(256) void kg_scores() {
    gemm_dev(g_qk, 1024, g_Krel, EE, 0, nullptr, nullptr, 0, g_scores, NSC, BB, RR, EE);
}
__global__ __launch_bounds__(256) void kg_merged(const float* __restrict__ emb) {
    gemm_dev(g_scores, NSC, emb, EE, 1, nullptr, nullptr, 0, g_merged, EE, BB, EE, RR);
}

// ---- fused q|k GEMM: N=1024, W selects fcq (n<512) / fck (n>=512) ----
__global__ __launch_bounds__(256) void kg_qk(const float* __restrict__ fcqw, const float* __restrict__ fckw) {
    __shared__ float As[TM][TK + 1];
    __shared__ float Ws[TN][TK + 1];
    int tid = threadIdx.x;
    int mt = blockIdx.y * TM;
    int nt = blockIdx.x * TN;
    int tr = tid >> 4;
    int tc = tid & 15;
    float acc[2][4] = {{0.f,0.f,0.f,0.f},{0.f,0.f,0.f,0.f}};

    int ea = tid * 4;
    int ra = ea >> 5;
    int ka = ea & 31;
    int gmA = mt + ra;
    int ew = tid * 8;
    int rw = ew >> 5;
    int kw = ew & 31;
    int gnW = nt + rw;
    const float* Wrow = (gnW < EE) ? (fcqw + (size_t)gnW * EE) : (fckw + (size_t)(gnW - EE) * EE);

    for (int kt = 0; kt < EE; kt += TK) {
        #pragma unroll
        for (int i = 0; i < 4; i++)
            As[ra][ka + i] = g_hsel[(size_t)gmA * EE + kt + ka + i];
        #pragma unroll
        for (int i = 0; i < 8; i++)
            Ws[rw][kw + i] = Wrow[kt + kw + i];
        __syncthreads();
        #pragma unroll
        for (int kk = 0; kk < TK; kk++) {
            float a0 = As[2 * tr][kk];
            float a1 = As[2 * tr + 1][kk];
            float w0 = Ws[4 * tc + 0][kk];
            float w1 = Ws[4 * tc + 1][kk];
            float w2 = Ws[4 * tc + 2][kk];
            float w3 = Ws[4 * tc + 3][kk];
            acc[0][0] += a0 * w0; acc[0][1] += a0 * w1; acc[0][2] += a0 * w2; acc[0][3] += a0 * w3;
            acc[1][0] += a1 * w0; acc[1][1] += a1 * w1; acc[1][2] += a1 * w2; acc[1][3] += a1 * w3;
        }
        __syncthreads();
    }
    #pragma unroll
    for (int i = 0; i < 2; i++) {
        int gm = mt + 2 * tr + i;
        #pragma unroll
        for (int j = 0; j < 4; j++) {
            int gn = nt + 4 * tc + j;
            g_qk[(size_t)gm * 1024 + gn] = acc[i][j] + g_qbias[gn];
        }
    }
}

// ---- incremental GEMM: recompute G row (b*16+sel[b]) for all b; M=BB ----
__global__ __launch_bounds__(256) void kg_Gi(const float* __restrict__ wih) {
    __shared__ float As[TM][TK + 1];
    __shared__ float Ws[TN][TK + 1];
    int tid = threadIdx.x;
    int mt = blockIdx.y * TM;
    int nt = blockIdx.x * TN;
    int tr = tid >> 4;
    int tc = tid & 15;
    float acc[2][4] = {{0.f,0.f,0.f,0.f},{0.f,0.f,0.f,0.f}};

    int ea = tid * 4;
    int ra = ea >> 5;
    int ka = ea & 31;
    int gmA = mt + ra;                         // batch b (M=BB)
    int physA = gmA * SS + g_sel[gmA];         // sel in [0,14] -> in-bounds
    int ew = tid * 8;
    int rw = ew >> 5;
    int kw = ew & 31;
    int gnW = nt + rw;

    for (int kt = 0; kt < EE; kt += TK) {
        #pragma unroll
        for (int i = 0; i < 4; i++)
            As[ra][ka + i] = g_cur[(size_t)physA * EE + kt + ka + i];
        #pragma unroll
        for (int i = 0; i < 8; i++)
            Ws[rw][kw + i] = wih[(size_t)gnW * EE + kt + kw + i];
        __syncthreads();
        #pragma unroll
        for (int kk = 0; kk < TK; kk++) {
            float a0 = As[2 * tr][kk];
            float a1 = As[2 * tr + 1][kk];
            float w0 = Ws[4 * tc + 0][kk];
            float w1 = Ws[4 * tc + 1][kk];
            float w2 = Ws[4 * tc + 2][kk];
            float w3 = Ws[4 * tc + 3][kk];
            acc[0][0] += a0 * w0; acc[0][1] += a0 * w1; acc[0][2] += a0 * w2; acc[0][3] += a0 * w3;
            acc[1][0] += a1 * w0; acc[1][1] += a1 * w1; acc[1][2] += a1 * w2; acc[1][3] += a1 * w3;
        }
        __syncthreads();
    }
    #pragma unroll
    for (int i = 0; i < 2; i++) {
        int gm = mt + 2 * tr + i;
        int phys = gm * SS + g_sel[gm];
        #pragma unroll
        for (int j = 0; j < 4; j++) {
            int gn = nt + 4 * tc + j;
            g_G[(size_t)phys * G4 + gn] = acc[i][j] + g_blstm[gn];
        }
    }
}

// ---- incremental GEMM: g2 for 2 pairs/batch; M=2*BB=256 compact rows ----
__global__ __launch_bounds__(256) void kg_g2i(const float* __restrict__ whh) {
    __shared__ float As[TM][TK + 1];
    __shared__ float Ws[TN][TK + 1];
    int tid = threadIdx.x;
    int mt = blockIdx.y * TM;
    int nt = blockIdx.x * TN;
    int tr = tid >> 4;
    int tc = tid & 15;
    float acc[2][4] = {{0.f,0.f,0.f,0.f},{0.f,0.f,0.f,0.f}};

    int ea = tid * 4;
    int ra = ea >> 5;
    int ka = ea & 31;
    int gmA = mt + ra;                         // compact pair index m (M=256)
    int bA = gmA >> 1;
    int pA = g_sel[bA] - 1 + (gmA & 1);
    pA = min(max(pA, 0), 14);                  // clamp; invalid rows computed, never read
    int physA = bA * SS + pA;                  // h1 left row
    int ew = tid * 8;
    int rw = ew >> 5;
    int kw = ew & 31;
    int gnW = nt + rw;

    for (int kt = 0; kt < EE; kt += TK) {
        #pragma unroll
        for (int i = 0; i < 4; i++)
            As[ra][ka + i] = g_h1[(size_t)physA * EE + kt + ka + i];
        #pragma unroll
        for (int i = 0; i < 8; i++)
            Ws[rw][kw + i] = whh[(size_t)gnW * EE + kt + kw + i];
        __syncthreads();
        #pragma unroll
        for (int kk = 0; kk < TK; kk++) {
            float a0 = As[2 * tr][kk];
            float a1 = As[2 * tr + 1][kk];
            float w0 = Ws[4 * tc + 0][kk];
            float w1 = Ws[4 * tc + 1][kk];
            float w2 = Ws[4 * tc + 2][kk];
            float w3 = Ws[4 * tc + 3][kk];
            acc[0][0] += a0 * w0; acc[0][1] += a0 * w1; acc[0][2] += a0 * w2; acc[0][3] += a0 * w3;
            acc[1][0] += a1 * w0; acc[1][1] += a1 * w1; acc[1][2] += a1 * w2; acc[1][3] += a1 * w3;
        }
        __syncthreads();
    }
    #pragma unroll
    for (int i = 0; i < 2; i++) {
        int gm = mt + 2 * tr + i;
        int b = gm >> 1;
        int p = min(max(g_sel[b] - 1 + (gm & 1), 0), 14);
        size_t drow = (size_t)(b * SS + p + 1) * G4;       // G[left+1]
        #pragma unroll
        for (int j = 0; j < 4; j++) {
            int gn = nt + 4 * tc + j;
            g_g2[(size_t)gm * G4 + gn] = acc[i][j] + g_G[drow + gn];
        }
    }
}

// ================= LSTM elementwise =================
__global__ void k_h1() {
    int idx = blockIdx.x * blockDim.x + threadIdx.x;
    if (idx >= BB * SS * EE) return;
    int m = idx >> 9;
    int e = idx & (EE - 1);
    const float* g = g_G + (size_t)m * G4;
    float c = sigm(g[e]) * tanhf(g[1024 + e]);
    g_c1[idx] = c;
    g_h1[idx] = sigm(g[1536 + e]) * tanhf(c);
}

// incremental h1/c1: only the merged row per batch
__global__ void k_h1i() {
    int idx = blockIdx.x * blockDim.x + threadIdx.x;   // BB*EE
    if (idx >= BB * EE) return;
    int b = idx >> 9;
    int e = idx & (EE - 1);
    int phys = b * SS + g_sel[b];
    const float* g = g_G + (size_t)phys * G4;
    float c = sigm(g[e]) * tanhf(g[1024 + e]);
    g_c1[(size_t)phys * EE + e] = c;
    g_h1[(size_t)phys * EE + e] = sigm(g[1536 + e]) * tanhf(c);
}

__global__ __launch_bounds__(256) void k_h2() {
    int m = blockIdx.x;                 // 0..2046
    const float* g = g_g2 + (size_t)m * G4;
    __shared__ float red[256];
    float part = 0.f;
    for (int e = threadIdx.x; e < EE; e += 256) {
        float c = sigm(g[512 + e]) * g_c1[(size_t)m * EE + e] + sigm(g[e]) * tanhf(g[1024 + e]);
        float h = sigm(g[1536 + e]) * tanhf(c);
        g_h2[(size_t)m * EE + e] = h;
        part += h * g_fcw[e];
    }
    red[threadIdx.x] = part;
    __syncthreads();
    for (int s = 128; s > 0; s >>= 1) {
        if (threadIdx.x < s) red[threadIdx.x] += red[threadIdx.x + s];
        __syncthreads();
    }
    if (threadIdx.x == 0) g_sc[m] = sigm(red[0] + g_fcw[EE]);
}

// incremental h2/sc: 2 candidate pairs per batch; skip invalid
__global__ __launch_bounds__(256) void k_h2i(int L) {
    int m = blockIdx.x;                 // 0..255 compact
    int b = m >> 1;
    int t = m & 1;
    int s = g_sel[b];
    int p = s - 1 + t;
    bool valid = t == 0 ? (s >= 1) : (s <= L - 3);
    if (!valid) return;
    const float* g = g_g2 + (size_t)m * G4;
    int cr = b * SS + p;                // left row / pair row
    __shared__ float red[256];
    float part = 0.f;
    for (int e = threadIdx.x; e < EE; e += 256) {
        float c = sigm(g[512 + e]) * g_c1[(size_t)cr * EE + e] + sigm(g[e]) * tanhf(g[1024 + e]);
        float h = sigm(g[1536 + e]) * tanhf(c);
        g_h2[(size_t)cr * EE + e] = h;
        part += h * g_fcw[e];
    }
    red[threadIdx.x] = part;
    __syncthreads();
    for (int ss = 128; ss > 0; ss >>= 1) {
        if (threadIdx.x < ss) red[threadIdx.x] += red[threadIdx.x + ss];
        __syncthreads();
    }
    if (threadIdx.x == 0) g_sc[cr] = sigm(red[0] + g_fcw[EE]);
}

// ================= argmax + h-select =================
__global__ __launch_bounds__(64) void k_sel(int P) {
    int b = blockIdx.x;
    __shared__ int ssel;
    if (threadIdx.x == 0) {
        float best = -1e30f; int bi = 0;
        for (int p = 0; p < P; p++) {
            float v = g_sc[b * SS + p];
            if (v > best) { best = v; bi = p; }
        }
        g_sel[b] = bi; ssel = bi;
    }
    __syncthreads();
    int bi = ssel;
    for (int e = threadIdx.x; e < EE; e += 64)
        g_hsel[b * EE + e] = g_h2[(size_t)(b * SS + bi) * EE + e];
}

// ================= softmax / entropy =================
__global__ __launch_bounds__(256) void k_soft(int col, int finalFlag, float* __restrict__ out) {
    int b = blockIdx.x;
    __shared__ float sh[256];
    __shared__ float srow[NSC];
    float part = 0.f;
    for (int e = threadIdx.x; e < EE; e += 256)
        part += g_qk[(size_t)b * 1024 + e] * g_qk[(size_t)b * 1024 + 512 + e];
    sh[threadIdx.x] = part; __syncthreads();
    for (int s = 128; s > 0; s >>= 1) { if (threadIdx.x < s) sh[threadIdx.x] += sh[threadIdx.x + s]; __syncthreads(); }
    const float isq = 0.044194173824159216f;   // 1/sqrt(512)
    if (threadIdx.x == 0) srow[RR] = sh[0] * isq;
    __syncthreads();
    for (int i = threadIdx.x; i < RR; i += 256) srow[i] = g_scores[(size_t)b * NSC + i] * isq;
    __syncthreads();
    float mx = -1e30f;
    for (int i = threadIdx.x; i < NSC; i += 256) mx = fmaxf(mx, srow[i]);
    sh[threadIdx.x] = mx; __syncthreads();
    for (int s = 128; s > 0; s >>= 1) { if (threadIdx.x < s) sh[threadIdx.x] = fmaxf(sh[threadIdx.x], sh[threadIdx.x + s]); __syncthreads(); }
    mx = sh[0]; __syncthreads();
    float zp = 0.f;
    for (int i = threadIdx.x; i < NSC; i += 256) zp += expf(srow[i] - mx);
    sh[threadIdx.x] = zp; __syncthreads();
    for (int s = 128; s > 0; s >>= 1) { if (threadIdx.x < s) sh[threadIdx.x] += sh[threadIdx.x + s]; __syncthreads(); }
    float lse = mx + logf(sh[0]);
    __syncthreads();
    float ep = 0.f;
    for (int i = threadIdx.x; i < NSC; i += 256) {
        float p = expf(srow[i] - lse);
        ep += p * (lse - srow[i]);
        if (finalFlag) out[(size_t)b * NSC + i] = srow[i];
        else           g_scores[(size_t)b * NSC + i] = p;
    }
    sh[threadIdx.x] = ep; __syncthreads();
    for (int s = 128; s > 0; s >>= 1) { if (threadIdx.x < s) sh[threadIdx.x] += sh[threadIdx.x + s]; __syncthreads(); }
    if (threadIdx.x == 0) g_ent[b * SS + col] = sh[0];
}

// ================= merge + shift ALL state =================
__global__ __launch_bounds__(512) void k_upd(int L) {
    int b = blockIdx.x;
    int e = threadIdx.x;
    int s = g_sel[b];
    float p500 = g_scores[(size_t)b * NSC + RR];
    float newv = g_merged[(size_t)b * EE + e] + p500 * g_hsel[(size_t)b * EE + e];
    size_t base = (size_t)b * SS * EE;
    size_t gbase = (size_t)b * SS * G4;
    for (int j = s + 1; j <= L - 2; j++) {
        g_cur[base + (size_t)j * EE + e] = g_cur[base + (size_t)(j + 1) * EE + e];
        g_h1 [base + (size_t)j * EE + e] = g_h1 [base + (size_t)(j + 1) * EE + e];
        g_c1 [base + (size_t)j * EE + e] = g_c1 [base + (size_t)(j + 1) * EE + e];
        #pragma unroll
        for (int q = 0; q < 4; q++)
            g_G[gbase + (size_t)j * G4 + e + q * 512] = g_G[gbase + (size_t)(j + 1) * G4 + e + q * 512];
    }
    g_cur[base + (size_t)s * EE + e] = newv;
    for (int p = s + 1; p <= L - 3; p++)
        g_h2[base + (size_t)p * EE + e] = g_h2[base + (size_t)(p + 1) * EE + e];
    if (e == 0)
        for (int p = s + 1; p <= L - 3; p++) g_sc[b * SS + p] = g_sc[b * SS + p + 1];
}

// ================= loss-region writer =================
__global__ void k_out(float* __restrict__ out) {
    int j = blockIdx.x * blockDim.x + threadIdx.x;
    if (j >= NLOSS) return;
    out[OUT0 + j] = ((j & 15) == 14) ? 0.f : g_ent[j];
}

// ================= host launch =================
extern "C" void kernel_launch(void* const* d_in, const int* in_sizes, int n_in,
                              void* d_out, int out_size, void* d_ws, size_t ws_size,
                              hipStream_t stream) {
    const int*   tokens = (const int*)d_in[0];
    const float* emb    = (const float*)d_in[1];
    const float* wih    = (const float*)d_in[2];
    const float* whh    = (const float*)d_in[3];
    const float* bih    = (const float*)d_in[4];
    const float* bhh    = (const float*)d_in[5];
    const float* fcwv   = (const float*)d_in[6];
    const float* fcbv   = (const float*)d_in[7];
    const float* fcqw   = (const float*)d_in[8];
    const float* fcqb   = (const float*)d_in[9];
    const float* fckw   = (const float*)d_in[10];
    const float* fckb   = (const float*)d_in[11];
    float* out = (float*)d_out;

    auto grid2 = [](int M, int N) { return dim3((unsigned)((N + TN - 1) / TN), (unsigned)((M + TM - 1) / TM)); };

    k_prep<<<dim3(8), dim3(256), 0, stream>>>(bih, bhh, fcwv, fcbv, fcqb, fckb);
    kg_Krel<<<grid2(RR, EE), dim3(256), 0, stream>>>(emb, fckw);
    k_gather<<<dim3((BB * SS * EE + 255) / 256), dim3(256), 0, stream>>>(tokens, emb);

    // ---- initial full LSTM pass (once) ----
    kg_G<<<grid2(BB * SS, G4), dim3(256), 0, stream>>>(wih);
    k_h1<<<dim3((BB * SS * EE + 255) / 256), dim3(256), 0, stream>>>();
    kg_g2<<<grid2(NPAIR, G4), dim3(256), 0, stream>>>(whh);
    k_h2<<<dim3(NPAIR), dim3(256), 0, stream>>>();

    for (int L = SS; L >= 3; L--) {
        k_sel<<<dim3(BB), dim3(64), 0, stream>>>(L - 1);
        kg_qk<<<grid2(BB, 1024), dim3(256), 0, stream>>>(fcqw, fckw);
        kg_scores<<<grid2(BB, RR), dim3(256), 0, stream>>>();
        k_soft<<<dim3(BB), dim3(256), 0, stream>>>(SS - L, 0, out);
        kg_merged<<<grid2(BB, EE), dim3(256), 0, stream>>>(emb);
        k_upd<<<dim3(BB), dim3(512), 0, stream>>>(L);
        // ---- incremental recompute: merged row + <=2 adjacent pairs ----
        kg_Gi<<<grid2(BB, G4), dim3(256), 0, stream>>>(wih);
        k_h1i<<<dim3((BB * EE + 255) / 256), dim3(256), 0, stream>>>();
        kg_g2i<<<grid2(2 * BB, G4), dim3(256), 0, stream>>>(whh);
        k_h2i<<<dim3(2 * BB), dim3(256), 0, stream>>>(L);
    }

    // L == 2: pair 0's h2 is the final x
    k_sel<<<dim3(BB), dim3(64), 0, stream>>>(1);
    kg_qk<<<grid2(BB, 1024), dim3(256), 0, stream>>>(fcqw, fckw);
    kg_scores<<<grid2(BB, RR), dim3(256), 0, stream>>>();
    k_soft<<<dim3(BB), dim3(256), 0, stream>>>(15, 1, out);

    k_out<<<dim3(8), dim3(256), 0, stream>>>(out);

    (void)in_sizes; (void)n_in; (void)out_size; (void)d_ws; (void)ws_size;
}

// Round 12
// 2450.391 us; speedup vs baseline: 2.9822x; 1.3676x over previous
//
#include <hip/hip_runtime.h>
#include <hip/hip_bf16.h>

#define BB 128
#define SS 16
#define EE 512
#define RR 500
#define G4 2048          // 4*E
#define OUT0 64128       // B*501 : scores chunk first
#define NSC 501          // R+1
#define NLOSS 2048       // B*16
#define NPAIR 2047       // uniform pair rows m=0..2046 (p==15 junk, never read)
#define NSU 1012         // 500 scores | 512 u

__device__ __forceinline__ float sigm(float x) { return 1.f / (1.f + expf(-x)); }

// ================= device-global pipeline buffers =================
__device__ float g_blstm[G4];
__device__ float g_fcw[EE + 4];          // fc_w, fc_b at [EE]
__device__ float g_qbias[1024];          // fcq_b | fck_b
__device__ float g_Krel[RR * EE];
__device__ float g_cur[BB * SS * EE];    // strided rows m = b*16 + j
__device__ float g_G[BB * SS * G4];      // persistent, shifted incrementally
__device__ float g_h1[BB * SS * EE];
__device__ float g_c1[BB * SS * EE];
__device__ float g_h2[BB * SS * EE];     // pair p at row b*16+p
__device__ float g_g2[BB * SS * G4];     // init scratch; first 256 rows reused per-iter
__device__ float g_sc[BB * SS];
__device__ float g_ent[BB * SS];
__device__ int   g_sel[BB];
// attention precomputes + fused buffers
__device__ float g_fckwT[EE * EE];
__device__ float g_W2[RR * EE];          // W2[k,e] = sum_e' Krel[k,e'] fcq[e',e]
__device__ float g_Mx[EE * EE];          // Mx[f,e] = sum_e' fcq[e',e] fck[e',f]
__device__ float g_c2[RR + 4];           // c2[k] = Krel[k,:]·bq
__device__ float g_v1[EE];               // v1[e] = fck^T bq + fcq^T bk
__device__ float g_c0[1];                // bq·bk
__device__ float g_su[BB * NSU];         // per-iter: scores | u

// ================= setup =================
__global__ void k_prep(const float* __restrict__ bih, const float* __restrict__ bhh,
                       const float* __restrict__ fcwv, const float* __restrict__ fcbv,
                       const float* __restrict__ fcqb, const float* __restrict__ fckb) {
    int i = blockIdx.x * blockDim.x + threadIdx.x;   // grid 8*256 = 2048
    if (i < G4) g_blstm[i] = bih[i] + bhh[i];
    if (i < EE) {
        g_fcw[i] = fcwv[i];
        g_qbias[i] = fcqb[i];
        g_qbias[EE + i] = fckb[i];
    }
    if (i == 0) g_fcw[EE] = fcbv[0];
}

__global__ void k_gather(const int* __restrict__ tok, const float* __restrict__ emb) {
    int i = blockIdx.x * blockDim.x + threadIdx.x;
    if (i >= BB * SS * EE) return;
    int e = i & (EE - 1);
    int r = i >> 9;
    int t = tok[r];
    g_cur[i] = emb[(size_t)t * EE + e];
}

__global__ void k_tr(const float* __restrict__ fckw) {
    int i = blockIdx.x * blockDim.x + threadIdx.x;   // 512*512
    if (i >= EE * EE) return;
    int ep = i >> 9;           // e'
    int f = i & (EE - 1);
    g_fckwT[(size_t)f * EE + ep] = fckw[(size_t)ep * EE + f];
}

// c2 / v1 / c0 precompute. block 0: v1; block 1: c0; blocks 2..501: c2[blk-2]
__global__ __launch_bounds__(512) void k_vprep(const float* __restrict__ fcqw, const float* __restrict__ fckw) {
    __shared__ float sh[512];
    int t = threadIdx.x;
    int blk = blockIdx.x;
    if (blk == 0) {
        float acc = 0.f;
        for (int ep = 0; ep < EE; ep++)
            acc += g_qbias[ep] * fckw[(size_t)ep * EE + t] + g_qbias[EE + ep] * fcqw[(size_t)ep * EE + t];
        g_v1[t] = acc;
    } else if (blk == 1) {
        sh[t] = g_qbias[t] * g_qbias[EE + t];
        __syncthreads();
        for (int s = 256; s > 0; s >>= 1) { if (t < s) sh[t] += sh[t + s]; __syncthreads(); }
        if (t == 0) g_c0[0] = sh[0];
    } else {
        int k = blk - 2;
        sh[t] = g_Krel[(size_t)k * EE + t] * g_qbias[t];
        __syncthreads();
        for (int s = 256; s > 0; s >>= 1) { if (t < s) sh[t] += sh[t + s]; __syncthreads(); }
        if (t == 0) g_c2[k] = sh[0];
    }
}

// ================= fp32 GEMM tile core =================
#define TM 32
#define TN 64
#define TK 32
__device__ __forceinline__ void gemm_dev(
    const float* __restrict__ A, int lda,
    const float* __restrict__ W, int ldw, int wtrans,
    const float* __restrict__ bias, const float* __restrict__ Dadd, int ldd,
    float* __restrict__ C, int ldc, int M, int N, int K)
{
    __shared__ float As[TM][TK + 1];
    __shared__ float Ws[TN][TK + 1];
    int tid = threadIdx.x;
    int mt = blockIdx.y * TM;
    int nt = blockIdx.x * TN;
    int tr = tid >> 4;
    int tc = tid & 15;
    float acc[2][4] = {{0.f,0.f,0.f,0.f},{0.f,0.f,0.f,0.f}};

    int ea = tid * 4;
    int ra = ea >> 5;
    int ka = ea & 31;
    int gmA = mt + ra;
    bool rokA = gmA < M;
    int ew = tid * 8;
    int rw = ew >> 5;
    int kw = ew & 31;
    int gnW = nt + rw;
    bool rokW = gnW < N;

    for (int kt = 0; kt < K; kt += TK) {
        #pragma unroll
        for (int i = 0; i < 4; i++) {
            int gk = kt + ka + i;
            float v = 0.f;
            if (rokA && gk < K) v = A[(size_t)gmA * lda + gk];
            As[ra][ka + i] = v;
        }
        #pragma unroll
        for (int i = 0; i < 8; i++) {
            int gk = kt + kw + i;
            float v = 0.f;
            if (rokW && gk < K)
                v = wtrans ? W[(size_t)gk * ldw + gnW] : W[(size_t)gnW * ldw + gk];
            Ws[rw][kw + i] = v;
        }
        __syncthreads();
        #pragma unroll
        for (int kk = 0; kk < TK; kk++) {
            float a0 = As[2 * tr][kk];
            float a1 = As[2 * tr + 1][kk];
            float w0 = Ws[4 * tc + 0][kk];
            float w1 = Ws[4 * tc + 1][kk];
            float w2 = Ws[4 * tc + 2][kk];
            float w3 = Ws[4 * tc + 3][kk];
            acc[0][0] += a0 * w0; acc[0][1] += a0 * w1; acc[0][2] += a0 * w2; acc[0][3] += a0 * w3;
            acc[1][0] += a1 * w0; acc[1][1] += a1 * w1; acc[1][2] += a1 * w2; acc[1][3] += a1 * w3;
        }
        __syncthreads();
    }
    #pragma unroll
    for (int i = 0; i < 2; i++) {
        int gm = mt + 2 * tr + i;
        if (gm >= M) continue;
        #pragma unroll
        for (int j = 0; j < 4; j++) {
            int gn = nt + 4 * tc + j;
            if (gn >= N) continue;
            float v = acc[i][j];
            if (bias) v += bias[gn];
            if (Dadd) v += Dadd[(size_t)gm * ldd + gn];
            C[(size_t)gm * ldc + gn] = v;
        }
    }
}

// ---- full GEMM wrappers ----
__global__ __launch_bounds__(256) void kg_Krel(const float* __restrict__ emb, const float* __restrict__ fckw) {
    gemm_dev(emb, EE, fckw, EE, 0, g_qbias + EE, nullptr, 0, g_Krel, EE, RR, EE, EE);
}
__global__ __launch_bounds__(256) void kg_W2(const float* __restrict__ fcqw) {
    gemm_dev(g_Krel, EE, fcqw, EE, 1, nullptr, nullptr, 0, g_W2, EE, RR, EE, EE);
}
__global__ __launch_bounds__(256) void kg_Mx(const float* __restrict__ fcqw) {
    gemm_dev(g_fckwT, EE, fcqw, EE, 1, nullptr, nullptr, 0, g_Mx, EE, EE, EE, EE);
}
__global__ __launch_bounds__(256) void kg_G(const float* __restrict__ wih) {
    gemm_dev(g_cur, EE, wih, EE, 0, g_blstm, nullptr, 0, g_G, G4, BB * SS, G4, EE);
}
__global__ __launch_bounds__(256) void kg_g2(const float* __restrict__ whh) {
    gemm_dev(g_h1, EE, whh, EE, 0, nullptr, g_G + G4, G4, g_g2, G4, NPAIR, G4, EE);
}

// ---- fused scores|u GEMM: A row = h2[b*16+sel[b]], W dual-source, N=1012 ----
__global__ __launch_bounds__(256) void kg_su() {
    __shared__ float As[TM][TK + 1];
    __shared__ float Ws[TN][TK + 1];
    int tid = threadIdx.x;
    int mt = blockIdx.y * TM;
    int nt = blockIdx.x * TN;
    int tr = tid >> 4;
    int tc = tid & 15;
    float acc[2][4] = {{0.f,0.f,0.f,0.f},{0.f,0.f,0.f,0.f}};

    int ea = tid * 4;
    int ra = ea >> 5;
    int ka = ea & 31;
    int gmA = mt + ra;                       // batch (M=128 exact)
    int physA = gmA * SS + g_sel[gmA];
    int ew = tid * 8;
    int rw = ew >> 5;
    int kw = ew & 31;
    int gnW = nt + rw;
    bool rokW = gnW < NSU;
    const float* Wrow = nullptr;
    if (rokW) Wrow = (gnW < RR) ? (g_W2 + (size_t)gnW * EE) : (g_Mx + (size_t)(gnW - RR) * EE);

    for (int kt = 0; kt < EE; kt += TK) {
        #pragma unroll
        for (int i = 0; i < 4; i++)
            As[ra][ka + i] = g_h2[(size_t)physA * EE + kt + ka + i];
        #pragma unroll
        for (int i = 0; i < 8; i++)
            Ws[rw][kw + i] = rokW ? Wrow[kt + kw + i] : 0.f;
        __syncthreads();
        #pragma unroll
        for (int kk = 0; kk < TK; kk++) {
            float a0 = As[2 * tr][kk];
            float a1 = As[2 * tr + 1][kk];
            float w0 = Ws[4 * tc + 0][kk];
            float w1 = Ws[4 * tc + 1][kk];
            float w2 = Ws[4 * tc + 2][kk];
            float w3 = Ws[4 * tc + 3][kk];
            acc[0][0] += a0 * w0; acc[0][1] += a0 * w1; acc[0][2] += a0 * w2; acc[0][3] += a0 * w3;
            acc[1][0] += a1 * w0; acc[1][1] += a1 * w1; acc[1][2] += a1 * w2; acc[1][3] += a1 * w3;
        }
        __syncthreads();
    }
    #pragma unroll
    for (int i = 0; i < 2; i++) {
        int gm = mt + 2 * tr + i;
        #pragma unroll
        for (int j = 0; j < 4; j++) {
            int gn = nt + 4 * tc + j;
            if (gn >= NSU) continue;
            g_su[(size_t)gm * NSU + gn] = acc[i][j] + (gn < RR ? g_c2[gn] : 0.f);
        }
    }
}

// ---- incremental GEMM: recompute G row (b*16+sel[b]); M=BB ----
__global__ __launch_bounds__(256) void kg_Gi(const float* __restrict__ wih) {
    __shared__ float As[TM][TK + 1];
    __shared__ float Ws[TN][TK + 1];
    int tid = threadIdx.x;
    int mt = blockIdx.y * TM;
    int nt = blockIdx.x * TN;
    int tr = tid >> 4;
    int tc = tid & 15;
    float acc[2][4] = {{0.f,0.f,0.f,0.f},{0.f,0.f,0.f,0.f}};

    int ea = tid * 4;
    int ra = ea >> 5;
    int ka = ea & 31;
    int gmA = mt + ra;
    int physA = gmA * SS + g_sel[gmA];
    int ew = tid * 8;
    int rw = ew >> 5;
    int kw = ew & 31;
    int gnW = nt + rw;

    for (int kt = 0; kt < EE; kt += TK) {
        #pragma unroll
        for (int i = 0; i < 4; i++)
            As[ra][ka + i] = g_cur[(size_t)physA * EE + kt + ka + i];
        #pragma unroll
        for (int i = 0; i < 8; i++)
            Ws[rw][kw + i] = wih[(size_t)gnW * EE + kt + kw + i];
        __syncthreads();
        #pragma unroll
        for (int kk = 0; kk < TK; kk++) {
            float a0 = As[2 * tr][kk];
            float a1 = As[2 * tr + 1][kk];
            float w0 = Ws[4 * tc + 0][kk];
            float w1 = Ws[4 * tc + 1][kk];
            float w2 = Ws[4 * tc + 2][kk];
            float w3 = Ws[4 * tc + 3][kk];
            acc[0][0] += a0 * w0; acc[0][1] += a0 * w1; acc[0][2] += a0 * w2; acc[0][3] += a0 * w3;
            acc[1][0] += a1 * w0; acc[1][1] += a1 * w1; acc[1][2] += a1 * w2; acc[1][3] += a1 * w3;
        }
        __syncthreads();
    }
    #pragma unroll
    for (int i = 0; i < 2; i++) {
        int gm = mt + 2 * tr + i;
        int phys = gm * SS + g_sel[gm];
        #pragma unroll
        for (int j = 0; j < 4; j++) {
            int gn = nt + 4 * tc + j;
            g_G[(size_t)phys * G4 + gn] = acc[i][j] + g_blstm[gn];
        }
    }
}

// ---- incremental GEMM: g2 for 2 pairs/batch; M=2*BB ----
__global__ __launch_bounds__(256) void kg_g2i(const float* __restrict__ whh) {
    __shared__ float As[TM][TK + 1];
    __shared__ float Ws[TN][TK + 1];
    int tid = threadIdx.x;
    int mt = blockIdx.y * TM;
    int nt = blockIdx.x * TN;
    int tr = tid >> 4;
    int tc = tid & 15;
    float acc[2][4] = {{0.f,0.f,0.f,0.f},{0.f,0.f,0.f,0.f}};

    int ea = tid * 4;
    int ra = ea >> 5;
    int ka = ea & 31;
    int gmA = mt + ra;
    int bA = gmA >> 1;
    int pA = g_sel[bA] - 1 + (gmA & 1);
    pA = min(max(pA, 0), 14);
    int physA = bA * SS + pA;
    int ew = tid * 8;
    int rw = ew >> 5;
    int kw = ew & 31;
    int gnW = nt + rw;

    for (int kt = 0; kt < EE; kt += TK) {
        #pragma unroll
        for (int i = 0; i < 4; i++)
            As[ra][ka + i] = g_h1[(size_t)physA * EE + kt + ka + i];
        #pragma unroll
        for (int i = 0; i < 8; i++)
            Ws[rw][kw + i] = whh[(size_t)gnW * EE + kt + kw + i];
        __syncthreads();
        #pragma unroll
        for (int kk = 0; kk < TK; kk++) {
            float a0 = As[2 * tr][kk];
            float a1 = As[2 * tr + 1][kk];
            float w0 = Ws[4 * tc + 0][kk];
            float w1 = Ws[4 * tc + 1][kk];
            float w2 = Ws[4 * tc + 2][kk];
            float w3 = Ws[4 * tc + 3][kk];
            acc[0][0] += a0 * w0; acc[0][1] += a0 * w1; acc[0][2] += a0 * w2; acc[0][3] += a0 * w3;
            acc[1][0] += a1 * w0; acc[1][1] += a1 * w1; acc[1][2] += a1 * w2; acc[1][3] += a1 * w3;
        }
        __syncthreads();
    }
    #pragma unroll
    for (int i = 0; i < 2; i++) {
        int gm = mt + 2 * tr + i;
        int b = gm >> 1;
        int p = min(max(g_sel[b] - 1 + (gm & 1), 0), 14);
        size_t drow = (size_t)(b * SS + p + 1) * G4;
        #pragma unroll
        for (int j = 0; j < 4; j++) {
            int gn = nt + 4 * tc + j;
            g_g2[(size_t)gm * G4 + gn] = acc[i][j] + g_G[drow + gn];
        }
    }
}

// ================= LSTM elementwise =================
__global__ void k_h1() {
    int idx = blockIdx.x * blockDim.x + threadIdx.x;
    if (idx >= BB * SS * EE) return;
    int m = idx >> 9;
    int e = idx & (EE - 1);
    const float* g = g_G + (size_t)m * G4;
    float c = sigm(g[e]) * tanhf(g[1024 + e]);
    g_c1[idx] = c;
    g_h1[idx] = sigm(g[1536 + e]) * tanhf(c);
}

__global__ void k_h1i() {
    int idx = blockIdx.x * blockDim.x + threadIdx.x;   // BB*EE
    if (idx >= BB * EE) return;
    int b = idx >> 9;
    int e = idx & (EE - 1);
    int phys = b * SS + g_sel[b];
    const float* g = g_G + (size_t)phys * G4;
    float c = sigm(g[e]) * tanhf(g[1024 + e]);
    g_c1[(size_t)phys * EE + e] = c;
    g_h1[(size_t)phys * EE + e] = sigm(g[1536 + e]) * tanhf(c);
}

__global__ __launch_bounds__(256) void k_h2() {
    int m = blockIdx.x;                 // 0..2046
    const float* g = g_g2 + (size_t)m * G4;
    __shared__ float red[256];
    float part = 0.f;
    for (int e = threadIdx.x; e < EE; e += 256) {
        float c = sigm(g[512 + e]) * g_c1[(size_t)m * EE + e] + sigm(g[e]) * tanhf(g[1024 + e]);
        float h = sigm(g[1536 + e]) * tanhf(c);
        g_h2[(size_t)m * EE + e] = h;
        part += h * g_fcw[e];
    }
    red[threadIdx.x] = part;
    __syncthreads();
    for (int s = 128; s > 0; s >>= 1) {
        if (threadIdx.x < s) red[threadIdx.x] += red[threadIdx.x + s];
        __syncthreads();
    }
    if (threadIdx.x == 0) g_sc[m] = sigm(red[0] + g_fcw[EE]);
}

__global__ __launch_bounds__(256) void k_h2i(int L) {
    int m = blockIdx.x;                 // 0..255
    int b = m >> 1;
    int t = m & 1;
    int s = g_sel[b];
    int p = s - 1 + t;
    bool valid = t == 0 ? (s >= 1) : (s <= L - 3);
    if (!valid) return;
    const float* g = g_g2 + (size_t)m * G4;
    int cr = b * SS + p;
    __shared__ float red[256];
    float part = 0.f;
    for (int e = threadIdx.x; e < EE; e += 256) {
        float c = sigm(g[512 + e]) * g_c1[(size_t)cr * EE + e] + sigm(g[e]) * tanhf(g[1024 + e]);
        float h = sigm(g[1536 + e]) * tanhf(c);
        g_h2[(size_t)cr * EE + e] = h;
        part += h * g_fcw[e];
    }
    red[threadIdx.x] = part;
    __syncthreads();
    for (int ss = 128; ss > 0; ss >>= 1) {
        if (threadIdx.x < ss) red[threadIdx.x] += red[threadIdx.x + ss];
        __syncthreads();
    }
    if (threadIdx.x == 0) g_sc[cr] = sigm(red[0] + g_fcw[EE]);
}

// ================= argmax =================
__global__ void k_sel(int P) {
    int b = blockIdx.x * blockDim.x + threadIdx.x;
    if (b >= BB) return;
    float best = -1e30f; int bi = 0;
    for (int p = 0; p < P; p++) {
        float v = g_sc[b * SS + p];
        if (v > best) { best = v; bi = p; }
    }
    g_sel[b] = bi;
}

// ================= fused softmax + entropy + merged + shift =================
__global__ __launch_bounds__(512) void k_smu(int col, int finalFlag, int L,
                                             const float* __restrict__ emb, float* __restrict__ out) {
    int b = blockIdx.x;
    int t = threadIdx.x;      // 0..511
    __shared__ float sh[512];
    __shared__ float srow[NSC];
    __shared__ float s_p500;
    const float* su = g_su + (size_t)b * NSU;
    int s = g_sel[b];
    const float* h2row = g_h2 + (size_t)(b * SS + s) * EE;
    const float isq = 0.044194173824159216f;   // 1/sqrt(512)

    float hv = h2row[t];
    // q·k = h·(u+v1) + c0
    sh[t] = hv * (su[RR + t] + g_v1[t]);
    __syncthreads();
    for (int ss = 256; ss > 0; ss >>= 1) { if (t < ss) sh[t] += sh[t + ss]; __syncthreads(); }
    if (t == 0) srow[RR] = (sh[0] + g_c0[0]) * isq;
    __syncthreads();
    if (t < RR) srow[t] = su[t] * isq;
    __syncthreads();
    float mx = (t < NSC) ? srow[t] : -1e30f;
    sh[t] = mx; __syncthreads();
    for (int ss = 256; ss > 0; ss >>= 1) { if (t < ss) sh[t] = fmaxf(sh[t], sh[t + ss]); __syncthreads(); }
    mx = sh[0]; __syncthreads();
    float zp = (t < NSC) ? expf(srow[t] - mx) : 0.f;
    sh[t] = zp; __syncthreads();
    for (int ss = 256; ss > 0; ss >>= 1) { if (t < ss) sh[t] += sh[t + ss]; __syncthreads(); }
    float lse = mx + logf(sh[0]);
    __syncthreads();
    float p = (t < NSC) ? expf(srow[t] - lse) : 0.f;
    float ep = (t < NSC) ? p * (lse - srow[t]) : 0.f;
    if (finalFlag && t < NSC) out[(size_t)b * NSC + t] = srow[t];
    sh[t] = ep; __syncthreads();
    for (int ss = 256; ss > 0; ss >>= 1) { if (t < ss) sh[t] += sh[t + ss]; __syncthreads(); }
    if (t == 0) g_ent[b * SS + col] = sh[0];
    if (finalFlag) return;

    __syncthreads();
    if (t < NSC) srow[t] = p;            // prob in place
    if (t == RR) s_p500 = p;
    __syncthreads();
    // merged = prob[:500] @ emb
    float macc = 0.f;
    for (int k = 0; k < RR; k++) macc += srow[k] * emb[(size_t)k * EE + t];
    float newv = macc + s_p500 * hv;
    // shift state (rows > s), insert merged at s
    size_t base = (size_t)b * SS * EE;
    size_t gbase = (size_t)b * SS * G4;
    for (int j = s + 1; j <= L - 2; j++) {
        g_cur[base + (size_t)j * EE + t] = g_cur[base + (size_t)(j + 1) * EE + t];
        g_h1 [base + (size_t)j * EE + t] = g_h1 [base + (size_t)(j + 1) * EE + t];
        g_c1 [base + (size_t)j * EE + t] = g_c1 [base + (size_t)(j + 1) * EE + t];
        #pragma unroll
        for (int q = 0; q < 4; q++)
            g_G[gbase + (size_t)j * G4 + t + q * 512] = g_G[gbase + (size_t)(j + 1) * G4 + t + q * 512];
    }
    g_cur[base + (size_t)s * EE + t] = newv;
    for (int pp = s + 1; pp <= L - 3; pp++)
        g_h2[base + (size_t)pp * EE + t] = g_h2[base + (size_t)(pp + 1) * EE + t];
    if (t == 0)
        for (int pp = s + 1; pp <= L - 3; pp++) g_sc[b * SS + pp] = g_sc[b * SS + pp + 1];
}

// ================= loss-region writer =================
__global__ void k_out(float* __restrict__ out) {
    int j = blockIdx.x * blockDim.x + threadIdx.x;
    if (j >= NLOSS) return;
    out[OUT0 + j] = ((j & 15) == 14) ? 0.f : g_ent[j];
}

// ================= host launch =================
extern "C" void kernel_launch(void* const* d_in, const int* in_sizes, int n_in,
                              void* d_out, int out_size, void* d_ws, size_t ws_size,
                              hipStream_t stream) {
    const int*   tokens = (const int*)d_in[0];
    const float* emb    = (const float*)d_in[1];
    const float* wih    = (const float*)d_in[2];
    const float* whh    = (const float*)d_in[3];
    const float* bih    = (const float*)d_in[4];
    const float* bhh    = (const float*)d_in[5];
    const float* fcwv   = (const float*)d_in[6];
    const float* fcbv   = (const float*)d_in[7];
    const float* fcqw   = (const float*)d_in[8];
    const float* fcqb   = (const float*)d_in[9];
    const float* fckw   = (const float*)d_in[10];
    const float* fckb   = (const float*)d_in[11];
    float* out = (float*)d_out;

    auto grid2 = [](int M, int N) { return dim3((unsigned)((N + TN - 1) / TN), (unsigned)((M + TM - 1) / TM)); };

    // ---- setup + attention precomputes (once) ----
    k_prep<<<dim3(8), dim3(256), 0, stream>>>(bih, bhh, fcwv, fcbv, fcqb, fckb);
    kg_Krel<<<grid2(RR, EE), dim3(256), 0, stream>>>(emb, fckw);
    k_tr<<<dim3((EE * EE + 255) / 256), dim3(256), 0, stream>>>(fckw);
    kg_W2<<<grid2(RR, EE), dim3(256), 0, stream>>>(fcqw);
    kg_Mx<<<grid2(EE, EE), dim3(256), 0, stream>>>(fcqw);
    k_vprep<<<dim3(502), dim3(512), 0, stream>>>(fcqw, fckw);
    k_gather<<<dim3((BB * SS * EE + 255) / 256), dim3(256), 0, stream>>>(tokens, emb);

    // ---- initial full LSTM pass (once) ----
    kg_G<<<grid2(BB * SS, G4), dim3(256), 0, stream>>>(wih);
    k_h1<<<dim3((BB * SS * EE + 255) / 256), dim3(256), 0, stream>>>();
    kg_g2<<<grid2(NPAIR, G4), dim3(256), 0, stream>>>(whh);
    k_h2<<<dim3(NPAIR), dim3(256), 0, stream>>>();

    for (int L = SS; L >= 3; L--) {
        k_sel<<<dim3(2), dim3(64), 0, stream>>>(L - 1);
        kg_su<<<grid2(BB, NSU), dim3(256), 0, stream>>>();
        k_smu<<<dim3(BB), dim3(512), 0, stream>>>(SS - L, 0, L, emb, out);
        kg_Gi<<<grid2(BB, G4), dim3(256), 0, stream>>>(wih);
        k_h1i<<<dim3((BB * EE + 255) / 256), dim3(256), 0, stream>>>();
        kg_g2i<<<grid2(2 * BB, G4), dim3(256), 0, stream>>>(whh);
        k_h2i<<<dim3(2 * BB), dim3(256), 0, stream>>>(L);
    }

    // L == 2: pair 0's h2 is the final x
    k_sel<<<dim3(2), dim3(64), 0, stream>>>(1);
    kg_su<<<grid2(BB, NSU), dim3(256), 0, stream>>>();
    k_smu<<<dim3(BB), dim3(512), 0, stream>>>(15, 1, 2, emb, out);

    k_out<<<dim3(8), dim3(256), 0, stream>>>(out);

    (void)in_sizes; (void)n_in; (void)out_size; (void)d_ws; (void)ws_size;
}